// Round 2
// baseline (193.161 us; speedup 1.0000x reference)
//
#include <hip/hip_runtime.h>

// TripleGenerator: segmented triu-combinations, fused single kernel.
// out = [idx_i (12M) | idx_j (12M) | idx_k (12M)] int32, 144 MB pure-write.
//
// Layout: block = 960 threads = 32 atoms x 30 int4-groups (T_PER=120 -> 30 int4).
// Threads 0..31 lower_bound(pair_i, atom) -> LDS; all threads then write
// three coalesced 16B non-temporal stores. g = blockIdx*960 + tid.

constexpr int K       = 16;               // neighbors/atom (out_size/in_size ratio fixed)
constexpr int T_PER   = K * (K - 1) / 2;  // 120
constexpr int GROUPS  = T_PER / 4;        // 30 int4 groups per atom
constexpr int APB     = 32;               // atoms per block
constexpr int THREADS = APB * GROUPS;     // 960 = 15 waves

typedef int iv4 __attribute__((ext_vector_type(4)));

// Packed (u,v) template: entry r holds bytes {t=4r..4r+3} of pu in u[r], pv in v[r].
struct Tbl { unsigned u[GROUPS]; unsigned v[GROUPS]; };
constexpr Tbl make_tbl() {
    Tbl t{};
    int idx = 0;
    for (int a = 0; a < K; ++a)
        for (int b = a + 1; b < K; ++b) {
            t.u[idx / 4] |= (unsigned)a << ((idx % 4) * 8);
            t.v[idx / 4] |= (unsigned)b << ((idx % 4) * 8);
            ++idx;
        }
    return t;
}
__device__ constexpr Tbl TBL = make_tbl();

__global__ __launch_bounds__(THREADS, 2)
void triple_gen_fused(const int* __restrict__ pair_i, int* __restrict__ out,
                      int n_atoms, int m, int per_arr_groups) {
    __shared__ int s_start[APB];

    const int t  = threadIdx.x;
    const int a0 = blockIdx.x * APB;

    // Phase 1: starts[a] = lower_bound(pair_i, a) == cumsum(counts)-counts
    // for sorted pair_i (exact, incl. empty segments).
    if (t < APB) {
        int a = a0 + t;
        int lo = 0;
        if (a < n_atoms) {
            int hi = m;
            while (lo < hi) {
                int mid = (lo + hi) >> 1;
                if (pair_i[mid] < a) lo = mid + 1; else hi = mid;
            }
        }
        s_start[t] = lo;
    }
    __syncthreads();

    // Phase 2: one int4 group per thread, three streaming stores.
    const int local_atom = t / GROUPS;          // t<960: cheap const-div
    const int r          = t - local_atom * GROUPS;
    const int atom       = a0 + local_atom;
    if (atom >= n_atoms) return;                // exact for 100000/32, kept for safety

    const int start = s_start[local_atom];      // <=2-way LDS aliasing: free
    const unsigned ub = TBL.u[r];
    const unsigned vb = TBL.v[r];

    const int g = atom * GROUPS + r;            // == blockIdx.x*THREADS + t when exact
    iv4* o = (iv4*)out;

    iv4 vi; vi[0] = atom; vi[1] = atom; vi[2] = atom; vi[3] = atom;
    iv4 vj; vj[0] = start + (int)(ub & 0xff);
            vj[1] = start + (int)((ub >> 8)  & 0xff);
            vj[2] = start + (int)((ub >> 16) & 0xff);
            vj[3] = start + (int)((ub >> 24) & 0xff);
    iv4 vk; vk[0] = start + (int)(vb & 0xff);
            vk[1] = start + (int)((vb >> 8)  & 0xff);
            vk[2] = start + (int)((vb >> 16) & 0xff);
            vk[3] = start + (int)((vb >> 24) & 0xff);

    __builtin_nontemporal_store(vi, &o[g]);
    __builtin_nontemporal_store(vj, &o[g + per_arr_groups]);
    __builtin_nontemporal_store(vk, &o[g + 2 * per_arr_groups]);
}

extern "C" void kernel_launch(void* const* d_in, const int* in_sizes, int n_in,
                              void* d_out, int out_size, void* d_ws, size_t ws_size,
                              hipStream_t stream) {
    const int* pair_i  = (const int*)d_in[0];
    const int  m       = in_sizes[0];   // n_atoms * K
    const int  n_atoms = m / K;         // 100,000

    int* out = (int*)d_out;
    const int per_arr_groups = n_atoms * GROUPS;        // 3,000,000
    const int n_blocks = (n_atoms + APB - 1) / APB;     // 3125

    triple_gen_fused<<<n_blocks, THREADS, 0, stream>>>(pair_i, out, n_atoms, m,
                                                       per_arr_groups);
}

// Round 3
// 156.330 us; speedup vs baseline: 1.2356x; 1.2356x over previous
//
#include <hip/hip_runtime.h>

// TripleGenerator: segmented triu-combinations.
// out = [idx_i (12M) | idx_j (12M) | idx_k (12M)] int32, 144 MB pure-write.
//
// Two-kernel structure (R1, proven): pass 1 = fully-parallel per-atom
// lower_bound into d_ws; pass 2 = PERSISTENT grid-stride writer (this round's
// change): long-lived waves stream stores back-to-back like the runtime's
// fill kernel, instead of 47K one-shot waves (R1) or barrier-serialized
// searches (R2 regression).

constexpr int K      = 16;                // neighbors/atom
constexpr int T_PER  = K * (K - 1) / 2;   // 120
constexpr int GROUPS = T_PER / 4;         // 30 int4 groups per atom

typedef int iv4 __attribute__((ext_vector_type(4)));

// Packed (u,v) template: entry r holds bytes {t=4r..4r+3} of pu in u[r], pv in v[r].
struct Tbl { unsigned u[GROUPS]; unsigned v[GROUPS]; };
constexpr Tbl make_tbl() {
    Tbl t{};
    int idx = 0;
    for (int a = 0; a < K; ++a)
        for (int b = a + 1; b < K; ++b) {
            t.u[idx / 4] |= (unsigned)a << ((idx % 4) * 8);
            t.v[idx / 4] |= (unsigned)b << ((idx % 4) * 8);
            ++idx;
        }
    return t;
}
__device__ constexpr Tbl TBL = make_tbl();

// Pass 1: starts[a] = lower_bound(pair_i, a). Exact match of cumsum(counts)-counts
// for sorted pair_i (incl. empty segments). 100K independent threads, ~21 L2-cached
// dependent loads each, all in parallel: ~3 us.
__global__ void starts_kernel(const int* __restrict__ pair_i, int* __restrict__ starts,
                              int n_atoms, int m) {
    int a = blockIdx.x * blockDim.x + threadIdx.x;
    if (a >= n_atoms) return;
    int lo = 0, hi = m;
    while (lo < hi) {
        int mid = (lo + hi) >> 1;
        if (pair_i[mid] < a) lo = mid + 1; else hi = mid;
    }
    starts[a] = lo;
}

// Pass 2: persistent grid-stride writer. Each thread handles ~5.7 int4 groups;
// per group: 3 coalesced 16B stores into the three output streams.
__global__ __launch_bounds__(256)
void gen_kernel(const int* __restrict__ starts, int* __restrict__ out,
                int per_arr_groups) {
    const int stride = gridDim.x * blockDim.x;
    iv4* o = (iv4*)out;

    for (int g = blockIdx.x * blockDim.x + threadIdx.x; g < per_arr_groups; g += stride) {
        const int atom = g / GROUPS;           // magic-mul const-div
        const int r    = g - atom * GROUPS;
        const int start = starts[atom];        // L2-hit, 30-way shared per atom

        const unsigned ub = TBL.u[r];
        const unsigned vb = TBL.v[r];

        iv4 vi; vi[0] = atom; vi[1] = atom; vi[2] = atom; vi[3] = atom;
        iv4 vj; vj[0] = start + (int)(ub & 0xff);
                vj[1] = start + (int)((ub >> 8)  & 0xff);
                vj[2] = start + (int)((ub >> 16) & 0xff);
                vj[3] = start + (int)((ub >> 24) & 0xff);
        iv4 vk; vk[0] = start + (int)(vb & 0xff);
                vk[1] = start + (int)((vb >> 8)  & 0xff);
                vk[2] = start + (int)((vb >> 16) & 0xff);
                vk[3] = start + (int)((vb >> 24) & 0xff);

        o[g] = vi;
        o[g + per_arr_groups] = vj;
        o[g + 2 * per_arr_groups] = vk;
    }
}

extern "C" void kernel_launch(void* const* d_in, const int* in_sizes, int n_in,
                              void* d_out, int out_size, void* d_ws, size_t ws_size,
                              hipStream_t stream) {
    const int* pair_i  = (const int*)d_in[0];
    const int  m       = in_sizes[0];   // n_atoms * K
    const int  n_atoms = m / K;         // 100,000

    int* out = (int*)d_out;
    const int per_arr_groups = n_atoms * GROUPS;   // 3,000,000

    int* starts = (int*)d_ws;                      // 400 KB needed; ws is far larger
    {
        const int b1 = 256;
        starts_kernel<<<(n_atoms + b1 - 1) / b1, b1, 0, stream>>>(pair_i, starts, n_atoms, m);
    }

    // Persistent writer: 2048 blocks x 256 thr = 524288 threads, ~5.7 groups each.
    gen_kernel<<<2048, 256, 0, stream>>>(starts, out, per_arr_groups);
}

// Round 4
// 156.064 us; speedup vs baseline: 1.2377x; 1.0017x over previous
//
#include <hip/hip_runtime.h>

// TripleGenerator: segmented triu-combinations.
// out = [idx_i (12M) | idx_j (12M) | idx_k (12M)] int32, 144 MB pure-write.
//
// R4: stream-specialized persistent writers. Each block handles exactly ONE of
// the three output arrays (stream = blockIdx%3), so every wave writes a single
// contiguous ascending region -- same access shape as the runtime's 6.6 TB/s
// fill kernel. R3 (3 stores to streams 48MB apart per wave-iter) hit only
// ~2.4 TB/s; this isolates the per-wave stream-count variable.

constexpr int K      = 16;                // neighbors/atom
constexpr int T_PER  = K * (K - 1) / 2;   // 120
constexpr int GROUPS = T_PER / 4;         // 30 int4 groups per atom

typedef int iv4 __attribute__((ext_vector_type(4)));

// Packed (u,v) template: entry r holds bytes {t=4r..4r+3} of pu in u[r], pv in v[r].
struct Tbl { unsigned u[GROUPS]; unsigned v[GROUPS]; };
constexpr Tbl make_tbl() {
    Tbl t{};
    int idx = 0;
    for (int a = 0; a < K; ++a)
        for (int b = a + 1; b < K; ++b) {
            t.u[idx / 4] |= (unsigned)a << ((idx % 4) * 8);
            t.v[idx / 4] |= (unsigned)b << ((idx % 4) * 8);
            ++idx;
        }
    return t;
}
__device__ constexpr Tbl TBL = make_tbl();

// Pass 1: starts[a] = lower_bound(pair_i, a). Exact match of cumsum(counts)-counts
// for sorted pair_i (incl. empty segments). ~5 us, fully parallel.
__global__ void starts_kernel(const int* __restrict__ pair_i, int* __restrict__ starts,
                              int n_atoms, int m) {
    int a = blockIdx.x * blockDim.x + threadIdx.x;
    if (a >= n_atoms) return;
    int lo = 0, hi = m;
    while (lo < hi) {
        int mid = (lo + hi) >> 1;
        if (pair_i[mid] < a) lo = mid + 1; else hi = mid;
    }
    starts[a] = lo;
}

// Pass 2: persistent, stream-specialized. Block-uniform branch on stream id.
__global__ __launch_bounds__(256)
void gen_split(const int* __restrict__ starts, int* __restrict__ out,
               int per_arr_groups) {
    const int s      = blockIdx.x % 3;            // stream id (mixes streams across XCDs)
    const int b      = blockIdx.x / 3;
    const int nb3    = gridDim.x / 3;             // blocks per stream
    const int stride = nb3 * blockDim.x;

    iv4* o = (iv4*)out + (size_t)s * per_arr_groups;

    if (s == 0) {
        for (int g = b * blockDim.x + threadIdx.x; g < per_arr_groups; g += stride) {
            const int atom = g / GROUPS;           // magic-mul const-div
            iv4 v; v[0] = atom; v[1] = atom; v[2] = atom; v[3] = atom;
            o[g] = v;
        }
    } else {
        const unsigned* __restrict__ tb = (s == 1) ? TBL.u : TBL.v;
        for (int g = b * blockDim.x + threadIdx.x; g < per_arr_groups; g += stride) {
            const int atom  = g / GROUPS;
            const int r     = g - atom * GROUPS;
            const int start = starts[atom];        // L2-hit, heavily shared
            const unsigned ub = tb[r];             // 120B L1-resident table
            iv4 v;
            v[0] = start + (int)(ub & 0xff);
            v[1] = start + (int)((ub >> 8)  & 0xff);
            v[2] = start + (int)((ub >> 16) & 0xff);
            v[3] = start + (int)((ub >> 24) & 0xff);
            o[g] = v;
        }
    }
}

extern "C" void kernel_launch(void* const* d_in, const int* in_sizes, int n_in,
                              void* d_out, int out_size, void* d_ws, size_t ws_size,
                              hipStream_t stream) {
    const int* pair_i  = (const int*)d_in[0];
    const int  m       = in_sizes[0];   // n_atoms * K
    const int  n_atoms = m / K;         // 100,000

    int* out = (int*)d_out;
    const int per_arr_groups = n_atoms * GROUPS;   // 3,000,000

    int* starts = (int*)d_ws;                      // 400 KB of scratch
    {
        const int b1 = 256;
        starts_kernel<<<(n_atoms + b1 - 1) / b1, b1, 0, stream>>>(pair_i, starts, n_atoms, m);
    }

    // 3072 blocks: 1024 per stream, 256 thr, ~11.4 int4-groups per thread.
    gen_split<<<3072, 256, 0, stream>>>(starts, out, per_arr_groups);
}